// Round 1
// 2095.668 us; speedup vs baseline: 1.0819x; 1.0819x over previous
//
#include <hip/hip_runtime.h>
#include <hip/hip_bf16.h>

// Problem constants
#define S_LEN 2048
#define NHEAD 32     // heads per batch
#define HDIM  128
#define HSZ   4096
#define NH_TOT 64    // B * NH
#define INV_NORM 0.08838834764831845f       // 1/sqrt(128)
#define NEG_MIN  -3.4028234663852886e38f    // finfo(float32).min
#define LOG2E    1.4426950408889634f

typedef __attribute__((ext_vector_type(8))) __bf16 bf16x8;
typedef __attribute__((ext_vector_type(4))) float  floatx4;

__device__ __forceinline__ float bf2f(__hip_bfloat16 x) { return __bfloat162float(x); }

// async 16B global->LDS. lds ptr must be wave-uniform; HW scatters lane i to base + i*16.
__device__ __forceinline__ void gload16(const void* g, void* l) {
  __builtin_amdgcn_global_load_lds(
      (__attribute__((address_space(1))) void*)g,
      (__attribute__((address_space(3))) void*)l, 16, 0, 0);
}

// ---------------------------------------------------------------------------
// f32 -> bf16 conversion (vectorized, 4 elems/thread)
// ---------------------------------------------------------------------------
__global__ __launch_bounds__(256) void cvt_f32_bf16(
    const float* __restrict__ in, __hip_bfloat16* __restrict__ out, size_t n)
{
  const size_t i = ((size_t)blockIdx.x * 256 + threadIdx.x) * 4;
  if (i < n) {
    const float4 v = *(const float4*)(in + i);
    __hip_bfloat16 o0 = __float2bfloat16(v.x);
    __hip_bfloat16 o1 = __float2bfloat16(v.y);
    __hip_bfloat16 o2 = __float2bfloat16(v.z);
    __hip_bfloat16 o3 = __float2bfloat16(v.w);
    ushort4 pk;
    pk.x = *(unsigned short*)&o0; pk.y = *(unsigned short*)&o1;
    pk.z = *(unsigned short*)&o2; pk.w = *(unsigned short*)&o3;
    *(ushort4*)(out + i) = pk;
  }
}

// ---------------------------------------------------------------------------
// mask bit-pack: int32 [2,2048,2048] -> u64 bitmask [2,2048,32]
// bit j of word w = (mask[flat = w*64 + j] != 0)
// ---------------------------------------------------------------------------
__global__ __launch_bounds__(256) void pack_mask(
    const int* __restrict__ mk, unsigned long long* __restrict__ mp)
{
  const size_t gid = (size_t)blockIdx.x * 256 + threadIdx.x;
  const unsigned long long b = __ballot(mk[gid] != 0);
  if ((threadIdx.x & 63) == 0) mp[gid >> 6] = b;
}

// ---------------------------------------------------------------------------
// QKV GEMM: C[4096, 12288] = hidden[4096,4096] @ qkv_w[12288,4096]^T + qkv_b
// ---------------------------------------------------------------------------
__global__ __launch_bounds__(256) void qkv_gemm(
    const __hip_bfloat16* __restrict__ A,     // [4096, 4096] bf16
    const __hip_bfloat16* __restrict__ W,     // [12288, 4096] bf16
    const float* __restrict__ bias,           // [12288] f32
    __hip_bfloat16* __restrict__ Qb,
    __hip_bfloat16* __restrict__ Kb,
    __hip_bfloat16* __restrict__ Vt)
{
  __shared__ __align__(16) __hip_bfloat16 As[128 * 32];
  __shared__ __align__(16) __hip_bfloat16 Bs[128 * 32];
  const int K  = 4096;
  const int m0 = blockIdx.y * 128;
  const int n0 = blockIdx.x * 128;
  const int t  = threadIdx.x;
  const int w  = t >> 6;
  const int l  = t & 63;
  const int wr = w >> 1, wc = w & 1;
  const int quad = l >> 4, ln = l & 15;

  floatx4 acc[4][4] = {};

  const int r1 = t >> 2,         c1 = (t & 3) * 8;
  const int r2 = (t >> 2) + 64,  c2 = (t & 3) * 8;
  char* AsB = (char*)As;
  char* BsB = (char*)Bs;
  const int wb1 = (w * 64) * 16;
  const int wb2 = (256 + w * 64) * 16;

  for (int k0 = 0; k0 < K; k0 += 32) {
    gload16(A + (size_t)(m0 + r1) * K + k0 + c1, AsB + wb1);
    gload16(W + (size_t)(n0 + r1) * K + k0 + c1, BsB + wb1);
    gload16(A + (size_t)(m0 + r2) * K + k0 + c2, AsB + wb2);
    gload16(W + (size_t)(n0 + r2) * K + k0 + c2, BsB + wb2);
    __syncthreads();
    bf16x8 af[4], bfr[4];
#pragma unroll
    for (int i = 0; i < 4; ++i)
      af[i] = *(const bf16x8*)(As + (wr * 64 + i * 16 + ln) * 32 + quad * 8);
#pragma unroll
    for (int j = 0; j < 4; ++j)
      bfr[j] = *(const bf16x8*)(Bs + (wc * 64 + j * 16 + ln) * 32 + quad * 8);
#pragma unroll
    for (int i = 0; i < 4; ++i)
#pragma unroll
      for (int j = 0; j < 4; ++j)
        acc[i][j] = __builtin_amdgcn_mfma_f32_16x16x32_bf16(af[i], bfr[j], acc[i][j], 0, 0, 0);
    __syncthreads();
  }

  // epilogue: n -> (nh, which, hd); m -> (b, s)
#pragma unroll
  for (int i = 0; i < 4; ++i) {
#pragma unroll
    for (int j = 0; j < 4; ++j) {
      const int n     = n0 + wc * 64 + j * 16 + ln;
      const int nh    = n / 384;
      const int which = (n >> 7) % 3;
      const int hd    = n & 127;
      const float bv  = bias[n];
#pragma unroll
      for (int r = 0; r < 4; ++r) {
        const int m  = m0 + wr * 64 + i * 16 + quad * 4 + r;
        const int bb = m >> 11;
        const int s  = m & 2047;
        const int head = bb * NHEAD + nh;
        const __hip_bfloat16 hv = __float2bfloat16(acc[i][j][r] + bv);
        if (which == 0)      Qb[((size_t)head * S_LEN + s) * HDIM + hd] = hv;
        else if (which == 1) Kb[((size_t)head * S_LEN + s) * HDIM + hd] = hv;
        else                 Vt[((size_t)head * HDIM + hd) * S_LEN + s] = hv;
      }
    }
  }
}

// ---------------------------------------------------------------------------
// Flash attention. One block per (head, 64 q-rows); 4 waves x 16 q-rows each.
// KVBLK=64. Softmax in log2 domain (v_exp_f32). Mask bit-packed.
// P staging LDS is wave-private -> NO block barriers in the KV loop
// (same-wave DS ops execute in order at the LDS unit).
// O overwrites the Q region in place (each block touches only its own rows).
// ---------------------------------------------------------------------------
__global__ __launch_bounds__(256) void flash_attn(
    __hip_bfloat16* __restrict__ Qb,           // [64, 2048, 128] in, O out
    const __hip_bfloat16* __restrict__ Kb,     // [64, 2048, 128]
    const __hip_bfloat16* __restrict__ Vt,     // [64, 128, 2048]
    const float* __restrict__ alibi,           // [64, 2048] f32
    const unsigned long long* __restrict__ mpack)  // [2, 2048, 32] u64 bitmask
{
  // per-wave P buffer: 16 rows x 64 cols, row stride 72 elems (144 B) to break
  // the D-stride bank conflict on ds_read_b128 (<=2-way aliasing, free).
  __shared__ __align__(16) __hip_bfloat16 Psh[4][16 * 72];
  const int head = blockIdx.x >> 5;
  const int qblk = blockIdx.x & 31;
  const int t = threadIdx.x;
  const int w = t >> 6, l = t & 63;
  const int quad = l >> 4, ln = l & 15;
  const int b = head >> 5;
  const int q0 = qblk * 64 + w * 16;

  __hip_bfloat16* Qh = Qb + (size_t)head * S_LEN * HDIM;
  const __hip_bfloat16* Kh = Kb + (size_t)head * S_LEN * HDIM;
  const __hip_bfloat16* Vh = Vt + (size_t)head * HDIM * S_LEN;
  const float* al = alibi + (size_t)head * S_LEN;
  const unsigned long long* mkp = mpack + (size_t)b * S_LEN * (S_LEN / 64);

  // Q fragments (A-operand): lane holds Q[q0+ln][ks*32 + quad*8 + j]
  bf16x8 qf[4];
#pragma unroll
  for (int ks = 0; ks < 4; ++ks)
    qf[ks] = *(const bf16x8*)(Qh + (size_t)(q0 + ln) * HDIM + ks * 32 + quad * 8);

  float m_run[4], lpart[4], alp[4], sv[4][4];
  floatx4 accO[8] = {};
#pragma unroll
  for (int r = 0; r < 4; ++r) { m_run[r] = -INFINITY; lpart[r] = 0.f; }

  __hip_bfloat16* Pw = Psh[w];
  const float SC = INV_NORM * LOG2E;   // fold log2(e) into the scale

  for (int kj0 = 0; kj0 < S_LEN; kj0 += 64) {
    // mask bits: one u64 per q-row covers kv columns [kj0, kj0+64)
    unsigned long long mb[4];
#pragma unroll
    for (int r = 0; r < 4; ++r)
      mb[r] = mkp[(size_t)(q0 + quad * 4 + r) * (S_LEN / 64) + (kj0 >> 6)];

    // scores: four 16-col tiles
#pragma unroll
    for (int tt = 0; tt < 4; ++tt) {
      const int kjb = kj0 + tt * 16;
      floatx4 accS = {};
#pragma unroll
      for (int ks = 0; ks < 4; ++ks) {
        bf16x8 kf = *(const bf16x8*)(Kh + (size_t)(kjb + ln) * HDIM + ks * 32 + quad * 8);
        accS = __builtin_amdgcn_mfma_f32_16x16x32_bf16(qf[ks], kf, accS, 0, 0, 0);
      }
      const float av = al[kjb + ln] * LOG2E;
#pragma unroll
      for (int r = 0; r < 4; ++r) {
        float s = accS[r] * SC + av;
        if ((mb[r] >> (tt * 16 + ln)) & 1ull) s = NEG_MIN;   // unscaled: just "very negative"
        sv[tt][r] = s;
      }
    }

    // online softmax, log2 domain (row spread over 16 lanes; xor 1,2,4,8)
    bool resc = false;
#pragma unroll
    for (int r = 0; r < 4; ++r) {
      float cm = fmaxf(fmaxf(sv[0][r], sv[1][r]), fmaxf(sv[2][r], sv[3][r]));
      cm = fmaxf(cm, __shfl_xor(cm, 1, 64));
      cm = fmaxf(cm, __shfl_xor(cm, 2, 64));
      cm = fmaxf(cm, __shfl_xor(cm, 4, 64));
      cm = fmaxf(cm, __shfl_xor(cm, 8, 64));
      const float mn = fmaxf(m_run[r], cm);
      const float a  = __builtin_amdgcn_exp2f(m_run[r] - mn);  // ==1.0 exactly when max unchanged
      alp[r] = a;
      if (a != 1.f) resc = true;
      m_run[r] = mn;
      float ps = 0.f;
#pragma unroll
      for (int tt = 0; tt < 4; ++tt) {
        const float p = __builtin_amdgcn_exp2f(sv[tt][r] - mn);
        sv[tt][r] = p;
        ps += p;
      }
      // per-lane partial l; cross-lane reduce deferred to epilogue
      lpart[r] = lpart[r] * a + ps;
    }
    if (__any(resc)) {
#pragma unroll
      for (int dt = 0; dt < 8; ++dt)
#pragma unroll
        for (int r = 0; r < 4; ++r) accO[dt][r] *= alp[r];
    }

    // P: C/D layout -> LDS (wave-private) -> A-operand layout
#pragma unroll
    for (int tt = 0; tt < 4; ++tt)
#pragma unroll
      for (int r = 0; r < 4; ++r)
        Pw[(quad * 4 + r) * 72 + tt * 16 + ln] = __float2bfloat16(sv[tt][r]);
    __builtin_amdgcn_wave_barrier();
    const bf16x8 pf0 = *(const bf16x8*)(Pw + ln * 72 + quad * 8);
    const bf16x8 pf1 = *(const bf16x8*)(Pw + ln * 72 + 32 + quad * 8);

    // PV: accO[dt] covers d = dt*16 + ln; two k-halves of the 64-wide tile
#pragma unroll
    for (int dt = 0; dt < 8; ++dt) {
      bf16x8 vf0 = *(const bf16x8*)(Vh + (size_t)(dt * 16 + ln) * S_LEN + kj0 + quad * 8);
      bf16x8 vf1 = *(const bf16x8*)(Vh + (size_t)(dt * 16 + ln) * S_LEN + kj0 + 32 + quad * 8);
      accO[dt] = __builtin_amdgcn_mfma_f32_16x16x32_bf16(pf0, vf0, accO[dt], 0, 0, 0);
      accO[dt] = __builtin_amdgcn_mfma_f32_16x16x32_bf16(pf1, vf1, accO[dt], 0, 0, 0);
    }
    __builtin_amdgcn_wave_barrier();
  }

  // epilogue: reduce l across the 16 lanes once, write O over this block's Q rows
#pragma unroll
  for (int r = 0; r < 4; ++r) {
    float ps = lpart[r];
    ps += __shfl_xor(ps, 1, 64);
    ps += __shfl_xor(ps, 2, 64);
    ps += __shfl_xor(ps, 4, 64);
    ps += __shfl_xor(ps, 8, 64);
    const int qi = q0 + quad * 4 + r;
    const float invl = 1.0f / ps;
#pragma unroll
    for (int dt = 0; dt < 8; ++dt)
      Qh[(size_t)qi * HDIM + dt * 16 + ln] = __float2bfloat16(accO[dt][r] * invl);
  }
}

// ---------------------------------------------------------------------------
// Dense GEMM: out[4096,4096] = ctx @ dense_w^T + dense_b + residual.
// ---------------------------------------------------------------------------
__global__ __launch_bounds__(256) void dense_gemm(
    const __hip_bfloat16* __restrict__ CtxQ,   // head-major ctx (Q region)
    const __hip_bfloat16* __restrict__ W,      // [4096, 4096] bf16
    const float* __restrict__ bias,            // [4096] f32
    const float* __restrict__ residual,        // [4096, 4096] f32
    float* __restrict__ out)                   // [4096, 4096] f32
{
  __shared__ __align__(16) __hip_bfloat16 As[128 * 32];
  __shared__ __align__(16) __hip_bfloat16 Bs[128 * 32];
  const int K  = 4096;
  const int m0 = blockIdx.y * 128;
  const int n0 = blockIdx.x * 128;
  const int t  = threadIdx.x;
  const int w  = t >> 6;
  const int l  = t & 63;
  const int wr = w >> 1, wc = w & 1;
  const int quad = l >> 4, ln = l & 15;

  floatx4 acc[4][4] = {};
  const int r1 = t >> 2,        c1 = (t & 3) * 8;
  const int r2 = (t >> 2) + 64, c2 = (t & 3) * 8;
  char* AsB = (char*)As;
  char* BsB = (char*)Bs;
  const int wb1 = (w * 64) * 16;
  const int wb2 = (256 + w * 64) * 16;

  const int m1 = m0 + r1, b1 = m1 >> 11, s1 = m1 & 2047;
  const int m2 = m0 + r2, b2 = m2 >> 11, s2 = m2 & 2047;

  for (int k0 = 0; k0 < K; k0 += 32) {
    const int nh  = k0 >> 7;
    const int hd0 = k0 & 127;
    gload16(CtxQ + ((size_t)((b1 * NHEAD + nh) * S_LEN + s1)) * HDIM + hd0 + c1, AsB + wb1);
    gload16(W + (size_t)(n0 + r1) * K + k0 + c1, BsB + wb1);
    gload16(CtxQ + ((size_t)((b2 * NHEAD + nh) * S_LEN + s2)) * HDIM + hd0 + c2, AsB + wb2);
    gload16(W + (size_t)(n0 + r2) * K + k0 + c2, BsB + wb2);
    __syncthreads();
    bf16x8 af[4], bfr[4];
#pragma unroll
    for (int i = 0; i < 4; ++i)
      af[i] = *(const bf16x8*)(As + (wr * 64 + i * 16 + ln) * 32 + quad * 8);
#pragma unroll
    for (int j = 0; j < 4; ++j)
      bfr[j] = *(const bf16x8*)(Bs + (wc * 64 + j * 16 + ln) * 32 + quad * 8);
#pragma unroll
    for (int i = 0; i < 4; ++i)
#pragma unroll
      for (int j = 0; j < 4; ++j)
        acc[i][j] = __builtin_amdgcn_mfma_f32_16x16x32_bf16(af[i], bfr[j], acc[i][j], 0, 0, 0);
    __syncthreads();
  }

#pragma unroll
  for (int i = 0; i < 4; ++i) {
#pragma unroll
    for (int j = 0; j < 4; ++j) {
      const int n = n0 + wc * 64 + j * 16 + ln;
      const float bv = bias[n];
#pragma unroll
      for (int r = 0; r < 4; ++r) {
        const int m = m0 + wr * 64 + i * 16 + quad * 4 + r;
        out[(size_t)m * HSZ + n] =
            acc[i][j][r] + bv + residual[(size_t)m * HSZ + n];
      }
    }
  }
}

extern "C" void kernel_launch(void* const* d_in, const int* in_sizes, int n_in,
                              void* d_out, int out_size, void* d_ws, size_t ws_size,
                              hipStream_t stream) {
  const float* hidden   = (const float*)d_in[0];
  const float* residual = (const float*)d_in[1];
  const float* alibi    = (const float*)d_in[2];
  const int*   mask     = (const int*)d_in[3];
  const float* qkv_w    = (const float*)d_in[4];
  const float* qkv_b    = (const float*)d_in[5];
  const float* dense_w  = (const float*)d_in[6];
  const float* dense_b  = (const float*)d_in[7];
  float* out = (float*)d_out;   // reference output dtype is float32

  // workspace (bf16): Qb/Kb/Vt (33.5 MB each), Ah (33.5 MB, reused for dense_w),
  // Wq (100.7 MB, reused for packed mask after qkv_gemm). Peak ≈ 235 MB.
  const size_t per  = (size_t)NH_TOT * S_LEN * HDIM;  // 16,777,216 elems
  const size_t nWq  = (size_t)3 * HSZ * HSZ;          // 50,331,648 elems
  __hip_bfloat16* Qb = (__hip_bfloat16*)d_ws;
  __hip_bfloat16* Kb = Qb + per;
  __hip_bfloat16* Vt = Kb + per;
  __hip_bfloat16* Ah = Vt + per;        // hidden bf16, later reused for dense_w
  __hip_bfloat16* Wq = Ah + per;        // qkv_w bf16; later reused for mask bits
  unsigned long long* mp = (unsigned long long*)Wq;   // 1 MB, after qkv_gemm

  // convert f32 inputs to bf16
  cvt_f32_bf16<<<(int)(per / 4 / 256), 256, 0, stream>>>(hidden, Ah, per);
  cvt_f32_bf16<<<(int)(nWq / 4 / 256), 256, 0, stream>>>(qkv_w, Wq, nWq);

  qkv_gemm<<<dim3(96, 32), 256, 0, stream>>>(Ah, Wq, qkv_b, Qb, Kb, Vt);

  // Wq dead now -> pack mask bits there; Ah dead -> reuse for dense_w bf16
  pack_mask<<<(int)(2u * S_LEN * S_LEN / 256), 256, 0, stream>>>(mask, mp);
  cvt_f32_bf16<<<(int)(per / 4 / 256), 256, 0, stream>>>(dense_w, Ah, per);

  flash_attn<<<dim3(2048), 256, 0, stream>>>(Qb, Kb, Vt, alibi, mp);
  dense_gemm<<<dim3(32, 32), 256, 0, stream>>>(Qb, Ah, dense_b, residual, out);
}

// Round 2
// 1500.766 us; speedup vs baseline: 1.5108x; 1.3964x over previous
//
#include <hip/hip_runtime.h>
#include <hip/hip_bf16.h>

// Problem constants
#define S_LEN 2048
#define NHEAD 32     // heads per batch
#define HDIM  128
#define HSZ   4096
#define NH_TOT 64    // B * NH
#define INV_NORM 0.08838834764831845f       // 1/sqrt(128)
#define NEG_MIN  -3.4028234663852886e38f    // finfo(float32).min
#define LOG2E    1.4426950408889634f

typedef __attribute__((ext_vector_type(8))) __bf16 bf16x8;
typedef __attribute__((ext_vector_type(4))) float  floatx4;

// async 16B global->LDS. lds ptr must be wave-uniform; HW scatters lane i to base + i*16.
__device__ __forceinline__ void gload16(const void* g, void* l) {
  __builtin_amdgcn_global_load_lds(
      (__attribute__((address_space(1))) void*)g,
      (__attribute__((address_space(3))) void*)l, 16, 0, 0);
}

// ---------------------------------------------------------------------------
// f32 -> bf16 conversion (vectorized, 4 elems/thread)
// ---------------------------------------------------------------------------
__global__ __launch_bounds__(256) void cvt_f32_bf16(
    const float* __restrict__ in, __hip_bfloat16* __restrict__ out, size_t n)
{
  const size_t i = ((size_t)blockIdx.x * 256 + threadIdx.x) * 4;
  if (i < n) {
    const float4 v = *(const float4*)(in + i);
    __hip_bfloat16 o0 = __float2bfloat16(v.x);
    __hip_bfloat16 o1 = __float2bfloat16(v.y);
    __hip_bfloat16 o2 = __float2bfloat16(v.z);
    __hip_bfloat16 o3 = __float2bfloat16(v.w);
    ushort4 pk;
    pk.x = *(unsigned short*)&o0; pk.y = *(unsigned short*)&o1;
    pk.z = *(unsigned short*)&o2; pk.w = *(unsigned short*)&o3;
    *(ushort4*)(out + i) = pk;
  }
}

// ---------------------------------------------------------------------------
// mask bit-pack: int32 [2,2048,2048] -> u64 bitmask [2,2048,32]
// ---------------------------------------------------------------------------
__global__ __launch_bounds__(256) void pack_mask(
    const int* __restrict__ mk, unsigned long long* __restrict__ mp)
{
  const size_t gid = (size_t)blockIdx.x * 256 + threadIdx.x;
  const unsigned long long b = __ballot(mk[gid] != 0);
  if ((threadIdx.x & 63) == 0) mp[gid >> 6] = b;
}

// ---------------------------------------------------------------------------
// QKV GEMM: C[4096, 12288] = hidden[4096,4096] @ qkv_w[12288,4096]^T + qkv_b
// ---------------------------------------------------------------------------
__global__ __launch_bounds__(256) void qkv_gemm(
    const __hip_bfloat16* __restrict__ A,     // [4096, 4096] bf16
    const __hip_bfloat16* __restrict__ W,     // [12288, 4096] bf16
    const float* __restrict__ bias,           // [12288] f32
    __hip_bfloat16* __restrict__ Qb,
    __hip_bfloat16* __restrict__ Kb,
    __hip_bfloat16* __restrict__ Vt)
{
  __shared__ __align__(16) __hip_bfloat16 As[128 * 32];
  __shared__ __align__(16) __hip_bfloat16 Bs[128 * 32];
  const int K  = 4096;
  const int m0 = blockIdx.y * 128;
  const int n0 = blockIdx.x * 128;
  const int t  = threadIdx.x;
  const int w  = t >> 6;
  const int l  = t & 63;
  const int wr = w >> 1, wc = w & 1;
  const int quad = l >> 4, ln = l & 15;

  floatx4 acc[4][4] = {};

  const int r1 = t >> 2,         c1 = (t & 3) * 8;
  const int r2 = (t >> 2) + 64,  c2 = (t & 3) * 8;
  char* AsB = (char*)As;
  char* BsB = (char*)Bs;
  const int wb1 = (w * 64) * 16;
  const int wb2 = (256 + w * 64) * 16;

  for (int k0 = 0; k0 < K; k0 += 32) {
    gload16(A + (size_t)(m0 + r1) * K + k0 + c1, AsB + wb1);
    gload16(W + (size_t)(n0 + r1) * K + k0 + c1, BsB + wb1);
    gload16(A + (size_t)(m0 + r2) * K + k0 + c2, AsB + wb2);
    gload16(W + (size_t)(n0 + r2) * K + k0 + c2, BsB + wb2);
    __syncthreads();
    bf16x8 af[4], bfr[4];
#pragma unroll
    for (int i = 0; i < 4; ++i)
      af[i] = *(const bf16x8*)(As + (wr * 64 + i * 16 + ln) * 32 + quad * 8);
#pragma unroll
    for (int j = 0; j < 4; ++j)
      bfr[j] = *(const bf16x8*)(Bs + (wc * 64 + j * 16 + ln) * 32 + quad * 8);
#pragma unroll
    for (int i = 0; i < 4; ++i)
#pragma unroll
      for (int j = 0; j < 4; ++j)
        acc[i][j] = __builtin_amdgcn_mfma_f32_16x16x32_bf16(af[i], bfr[j], acc[i][j], 0, 0, 0);
    __syncthreads();
  }

  // epilogue: n -> (nh, which, hd); m -> (b, s)
#pragma unroll
  for (int i = 0; i < 4; ++i) {
#pragma unroll
    for (int j = 0; j < 4; ++j) {
      const int n     = n0 + wc * 64 + j * 16 + ln;
      const int nh    = n / 384;
      const int which = (n >> 7) % 3;
      const int hd    = n & 127;
      const float bv  = bias[n];
#pragma unroll
      for (int r = 0; r < 4; ++r) {
        const int m  = m0 + wr * 64 + i * 16 + quad * 4 + r;
        const int bb = m >> 11;
        const int s  = m & 2047;
        const int head = bb * NHEAD + nh;
        const __hip_bfloat16 hv = __float2bfloat16(acc[i][j][r] + bv);
        if (which == 0)      Qb[((size_t)head * S_LEN + s) * HDIM + hd] = hv;
        else if (which == 1) Kb[((size_t)head * S_LEN + s) * HDIM + hd] = hv;
        else                 Vt[((size_t)head * HDIM + hd) * S_LEN + s] = hv;
      }
    }
  }
}

// ---------------------------------------------------------------------------
// Flash attention. One block per (head, 64 q-rows); 4 waves x 16 q-rows each.
// KVBLK=64. K/V tiles staged to LDS once per BLOCK (shared by all 4 waves),
// double-buffered, global_load_lds width=16, prefetch issued one tile ahead.
// LDS layout XOR-swizzled (chunk ^= row&7): linear gload_lds dest +
// inverse-swizzled GLOBAL source + same swizzle on ds_read (both-sides rule).
// Read patterns land 8 lanes per 4-bank group = 32 B/bank -> conflict-free.
// Softmax in log2 domain. Mask bit-packed. O overwrites Q region in place.
// ---------------------------------------------------------------------------
__global__ __launch_bounds__(256) void flash_attn(
    __hip_bfloat16* __restrict__ Qb,           // [64, 2048, 128] in, O out
    const __hip_bfloat16* __restrict__ Kb,     // [64, 2048, 128]
    const __hip_bfloat16* __restrict__ Vt,     // [64, 128, 2048]
    const float* __restrict__ alibi,           // [64, 2048] f32
    const unsigned long long* __restrict__ mpack)  // [2, 2048, 32] u64 bitmask
{
  // K tile: 64 kv-rows x 128 d (16 KB). V tile: 128 d-rows x 64 kv (16 KB).
  __shared__ __align__(16) __hip_bfloat16 KsS[2][64 * 128];
  __shared__ __align__(16) __hip_bfloat16 VsS[2][128 * 64];
  // per-wave P buffer: 16 rows x 64 cols, row stride 72 elems (144 B)
  __shared__ __align__(16) __hip_bfloat16 Psh[4][16 * 72];

  const int head = blockIdx.x >> 5;
  const int qblk = blockIdx.x & 31;
  const int t = threadIdx.x;
  const int w = t >> 6, l = t & 63;
  const int quad = l >> 4, ln = l & 15;
  const int b = head >> 5;
  const int q0 = qblk * 64 + w * 16;

  __hip_bfloat16* Qh = Qb + (size_t)head * S_LEN * HDIM;
  const __hip_bfloat16* Kh = Kb + (size_t)head * S_LEN * HDIM;
  const __hip_bfloat16* Vh = Vt + (size_t)head * HDIM * S_LEN;
  const float* al = alibi + (size_t)head * S_LEN;
  const unsigned long long* mkp = mpack + (size_t)b * S_LEN * (S_LEN / 64);

  // ---- staging: per wave, 4 gload16 for K + 4 for V; each call fills 64
  // consecutive 16B slots at a wave-uniform LDS base (lane i -> base + i*16).
  // K slot s: row = s>>4 (kv), chunk = s&15; source chunk = chunk ^ (row&7).
  // V slot s: row = s>>3 (d),  chunk = s&7;  source chunk = chunk ^ (row&7).
#define STAGE_KV(kj, Ks, Vs)                                                   \
  {                                                                            \
    _Pragma("unroll")                                                          \
    for (int c = 0; c < 4; ++c) {                                              \
      const int s   = (w * 4 + c) * 64 + l;                                    \
      const int row = s >> 4, ch = s & 15;                                     \
      const int g   = ch ^ (row & 7);                                          \
      gload16(Kh + (size_t)((kj) + row) * HDIM + g * 8,                        \
              (char*)(Ks) + (w * 4 + c) * 1024);                               \
    }                                                                          \
    _Pragma("unroll")                                                          \
    for (int c = 0; c < 4; ++c) {                                              \
      const int s   = (w * 4 + c) * 64 + l;                                    \
      const int row = s >> 3, ch = s & 7;                                      \
      const int g   = ch ^ (row & 7);                                          \
      gload16(Vh + (size_t)row * S_LEN + (kj) + g * 8,                         \
              (char*)(Vs) + (w * 4 + c) * 1024);                               \
    }                                                                          \
  }

  // prologue: stage tile 0; Q fragments load in the shadow
  STAGE_KV(0, KsS[0], VsS[0]);

  bf16x8 qf[4];
#pragma unroll
  for (int ks = 0; ks < 4; ++ks)
    qf[ks] = *(const bf16x8*)(Qh + (size_t)(q0 + ln) * HDIM + ks * 32 + quad * 8);

  float m_run[4], lpart[4], alp[4], sv[4][4];
  floatx4 accO[8] = {};
#pragma unroll
  for (int r = 0; r < 4; ++r) { m_run[r] = -INFINITY; lpart[r] = 0.f; }

  __hip_bfloat16* Pw = Psh[w];
  const float SC = INV_NORM * LOG2E;   // fold log2(e) into the scale
  const int ln7 = ln & 7;

  __syncthreads();   // tile 0 staged (drains vmcnt for all waves)

  for (int kj0 = 0, it = 0; kj0 < S_LEN; kj0 += 64, ++it) {
    const int cur = it & 1;
    const __hip_bfloat16* Kc = KsS[cur];
    const __hip_bfloat16* Vc = VsS[cur];

    // prefetch next tile into the other buffer (issued before all compute)
    if (kj0 + 64 < S_LEN) STAGE_KV(kj0 + 64, KsS[cur ^ 1], VsS[cur ^ 1]);

    // mask bits + alibi for this tile (small, L2-hot; issued early)
    unsigned long long mb[4];
#pragma unroll
    for (int r = 0; r < 4; ++r)
      mb[r] = mkp[(size_t)(q0 + quad * 4 + r) * (S_LEN / 64) + (kj0 >> 6)];
    float av[4];
#pragma unroll
    for (int tt = 0; tt < 4; ++tt)
      av[tt] = al[kj0 + tt * 16 + ln] * LOG2E;

    // scores: four 16-col tiles, K from LDS (swizzled)
#pragma unroll
    for (int tt = 0; tt < 4; ++tt) {
      floatx4 accS = {};
#pragma unroll
      for (int ks = 0; ks < 4; ++ks) {
        const int row = tt * 16 + ln;
        const int c   = (ks * 4 + quad) ^ ln7;
        bf16x8 kf = *(const bf16x8*)(Kc + row * 128 + c * 8);
        accS = __builtin_amdgcn_mfma_f32_16x16x32_bf16(qf[ks], kf, accS, 0, 0, 0);
      }
#pragma unroll
      for (int r = 0; r < 4; ++r) {
        float s = accS[r] * SC + av[tt];
        if ((mb[r] >> (tt * 16 + ln)) & 1ull) s = NEG_MIN;
        sv[tt][r] = s;
      }
    }

    // online softmax, log2 domain (row spread over 16 lanes; xor 1,2,4,8)
    bool resc = false;
#pragma unroll
    for (int r = 0; r < 4; ++r) {
      float cm = fmaxf(fmaxf(sv[0][r], sv[1][r]), fmaxf(sv[2][r], sv[3][r]));
      cm = fmaxf(cm, __shfl_xor(cm, 1, 64));
      cm = fmaxf(cm, __shfl_xor(cm, 2, 64));
      cm = fmaxf(cm, __shfl_xor(cm, 4, 64));
      cm = fmaxf(cm, __shfl_xor(cm, 8, 64));
      const float mn = fmaxf(m_run[r], cm);
      const float a  = __builtin_amdgcn_exp2f(m_run[r] - mn);
      alp[r] = a;
      if (a != 1.f) resc = true;
      m_run[r] = mn;
      float ps = 0.f;
#pragma unroll
      for (int tt = 0; tt < 4; ++tt) {
        const float p = __builtin_amdgcn_exp2f(sv[tt][r] - mn);
        sv[tt][r] = p;
        ps += p;
      }
      lpart[r] = lpart[r] * a + ps;   // per-lane partial l; reduced in epilogue
    }
    if (__any(resc)) {
#pragma unroll
      for (int dt = 0; dt < 8; ++dt)
#pragma unroll
        for (int r = 0; r < 4; ++r) accO[dt][r] *= alp[r];
    }

    // P: C/D layout -> LDS (wave-private) -> A-operand layout
#pragma unroll
    for (int tt = 0; tt < 4; ++tt)
#pragma unroll
      for (int r = 0; r < 4; ++r)
        Pw[(quad * 4 + r) * 72 + tt * 16 + ln] = __float2bfloat16(sv[tt][r]);
    __builtin_amdgcn_wave_barrier();
    const bf16x8 pf0 = *(const bf16x8*)(Pw + ln * 72 + quad * 8);
    const bf16x8 pf1 = *(const bf16x8*)(Pw + ln * 72 + 32 + quad * 8);

    // PV: accO[dt] covers d = dt*16 + ln; V from LDS (swizzled)
#pragma unroll
    for (int dt = 0; dt < 8; ++dt) {
      const int row = dt * 16 + ln;
      const int c0  = quad ^ ln7;
      const int c1  = (4 + quad) ^ ln7;
      bf16x8 vf0 = *(const bf16x8*)(Vc + row * 64 + c0 * 8);
      bf16x8 vf1 = *(const bf16x8*)(Vc + row * 64 + c1 * 8);
      accO[dt] = __builtin_amdgcn_mfma_f32_16x16x32_bf16(pf0, vf0, accO[dt], 0, 0, 0);
      accO[dt] = __builtin_amdgcn_mfma_f32_16x16x32_bf16(pf1, vf1, accO[dt], 0, 0, 0);
    }
    __builtin_amdgcn_wave_barrier();

    // end of tile: drain staging loads (compiler emits vmcnt(0) here) and
    // make next buffer visible to all waves; also fences buffer reuse.
    __syncthreads();
  }
#undef STAGE_KV

  // epilogue: reduce l across the 16 lanes once, write O over this block's Q rows
#pragma unroll
  for (int r = 0; r < 4; ++r) {
    float ps = lpart[r];
    ps += __shfl_xor(ps, 1, 64);
    ps += __shfl_xor(ps, 2, 64);
    ps += __shfl_xor(ps, 4, 64);
    ps += __shfl_xor(ps, 8, 64);
    const int qi = q0 + quad * 4 + r;
    const float invl = 1.0f / ps;
#pragma unroll
    for (int dt = 0; dt < 8; ++dt)
      Qh[(size_t)qi * HDIM + dt * 16 + ln] = __float2bfloat16(accO[dt][r] * invl);
  }
}

// ---------------------------------------------------------------------------
// Dense GEMM: out[4096,4096] = ctx @ dense_w^T + dense_b + residual.
// ---------------------------------------------------------------------------
__global__ __launch_bounds__(256) void dense_gemm(
    const __hip_bfloat16* __restrict__ CtxQ,   // head-major ctx (Q region)
    const __hip_bfloat16* __restrict__ W,      // [4096, 4096] bf16
    const float* __restrict__ bias,            // [4096] f32
    const float* __restrict__ residual,        // [4096, 4096] f32
    float* __restrict__ out)                   // [4096, 4096] f32
{
  __shared__ __align__(16) __hip_bfloat16 As[128 * 32];
  __shared__ __align__(16) __hip_bfloat16 Bs[128 * 32];
  const int K  = 4096;
  const int m0 = blockIdx.y * 128;
  const int n0 = blockIdx.x * 128;
  const int t  = threadIdx.x;
  const int w  = t >> 6;
  const int l  = t & 63;
  const int wr = w >> 1, wc = w & 1;
  const int quad = l >> 4, ln = l & 15;

  floatx4 acc[4][4] = {};
  const int r1 = t >> 2,        c1 = (t & 3) * 8;
  const int r2 = (t >> 2) + 64, c2 = (t & 3) * 8;
  char* AsB = (char*)As;
  char* BsB = (char*)Bs;
  const int wb1 = (w * 64) * 16;
  const int wb2 = (256 + w * 64) * 16;

  const int m1 = m0 + r1, b1 = m1 >> 11, s1 = m1 & 2047;
  const int m2 = m0 + r2, b2 = m2 >> 11, s2 = m2 & 2047;

  for (int k0 = 0; k0 < K; k0 += 32) {
    const int nh  = k0 >> 7;
    const int hd0 = k0 & 127;
    gload16(CtxQ + ((size_t)((b1 * NHEAD + nh) * S_LEN + s1)) * HDIM + hd0 + c1, AsB + wb1);
    gload16(W + (size_t)(n0 + r1) * K + k0 + c1, BsB + wb1);
    gload16(CtxQ + ((size_t)((b2 * NHEAD + nh) * S_LEN + s2)) * HDIM + hd0 + c2, AsB + wb2);
    gload16(W + (size_t)(n0 + r2) * K + k0 + c2, BsB + wb2);
    __syncthreads();
    bf16x8 af[4], bfr[4];
#pragma unroll
    for (int i = 0; i < 4; ++i)
      af[i] = *(const bf16x8*)(As + (wr * 64 + i * 16 + ln) * 32 + quad * 8);
#pragma unroll
    for (int j = 0; j < 4; ++j)
      bfr[j] = *(const bf16x8*)(Bs + (wc * 64 + j * 16 + ln) * 32 + quad * 8);
#pragma unroll
    for (int i = 0; i < 4; ++i)
#pragma unroll
      for (int j = 0; j < 4; ++j)
        acc[i][j] = __builtin_amdgcn_mfma_f32_16x16x32_bf16(af[i], bfr[j], acc[i][j], 0, 0, 0);
    __syncthreads();
  }

#pragma unroll
  for (int i = 0; i < 4; ++i) {
#pragma unroll
    for (int j = 0; j < 4; ++j) {
      const int n = n0 + wc * 64 + j * 16 + ln;
      const float bv = bias[n];
#pragma unroll
      for (int r = 0; r < 4; ++r) {
        const int m = m0 + wr * 64 + i * 16 + quad * 4 + r;
        out[(size_t)m * HSZ + n] =
            acc[i][j][r] + bv + residual[(size_t)m * HSZ + n];
      }
    }
  }
}

extern "C" void kernel_launch(void* const* d_in, const int* in_sizes, int n_in,
                              void* d_out, int out_size, void* d_ws, size_t ws_size,
                              hipStream_t stream) {
  const float* hidden   = (const float*)d_in[0];
  const float* residual = (const float*)d_in[1];
  const float* alibi    = (const float*)d_in[2];
  const int*   mask     = (const int*)d_in[3];
  const float* qkv_w    = (const float*)d_in[4];
  const float* qkv_b    = (const float*)d_in[5];
  const float* dense_w  = (const float*)d_in[6];
  const float* dense_b  = (const float*)d_in[7];
  float* out = (float*)d_out;   // reference output dtype is float32

  const size_t per  = (size_t)NH_TOT * S_LEN * HDIM;  // 16,777,216 elems
  const size_t nWq  = (size_t)3 * HSZ * HSZ;          // 50,331,648 elems
  __hip_bfloat16* Qb = (__hip_bfloat16*)d_ws;
  __hip_bfloat16* Kb = Qb + per;
  __hip_bfloat16* Vt = Kb + per;
  __hip_bfloat16* Ah = Vt + per;        // hidden bf16, later reused for dense_w
  __hip_bfloat16* Wq = Ah + per;        // qkv_w bf16; later reused for mask bits
  unsigned long long* mp = (unsigned long long*)Wq;   // 1 MB, after qkv_gemm

  // convert f32 inputs to bf16
  cvt_f32_bf16<<<(int)(per / 4 / 256), 256, 0, stream>>>(hidden, Ah, per);
  cvt_f32_bf16<<<(int)(nWq / 4 / 256), 256, 0, stream>>>(qkv_w, Wq, nWq);

  qkv_gemm<<<dim3(96, 32), 256, 0, stream>>>(Ah, Wq, qkv_b, Qb, Kb, Vt);

  // Wq dead now -> pack mask bits there; Ah dead -> reuse for dense_w bf16
  pack_mask<<<(int)(2u * S_LEN * S_LEN / 256), 256, 0, stream>>>(mask, mp);
  cvt_f32_bf16<<<(int)(per / 4 / 256), 256, 0, stream>>>(dense_w, Ah, per);

  flash_attn<<<dim3(2048), 256, 0, stream>>>(Qb, Kb, Vt, alibi, mp);
  dense_gemm<<<dim3(32, 32), 256, 0, stream>>>(Qb, Ah, dense_b, residual, out);
}

// Round 3
// 1288.273 us; speedup vs baseline: 1.7600x; 1.1649x over previous
//
#include <hip/hip_runtime.h>
#include <hip/hip_bf16.h>

// Problem constants
#define S_LEN 2048
#define NHEAD 32     // heads per batch
#define HDIM  128
#define HSZ   4096
#define NH_TOT 64    // B * NH
#define INV_NORM 0.08838834764831845f       // 1/sqrt(128)
#define NEG_MIN  -3.4028234663852886e38f    // finfo(float32).min
#define LOG2E    1.4426950408889634f

typedef __attribute__((ext_vector_type(8))) __bf16 bf16x8;
typedef __attribute__((ext_vector_type(4))) float  floatx4;

// async 16B global->LDS. lds ptr must be wave-uniform; HW scatters lane i to base + i*16.
__device__ __forceinline__ void gload16(const void* g, void* l) {
  __builtin_amdgcn_global_load_lds(
      (__attribute__((address_space(1))) void*)g,
      (__attribute__((address_space(3))) void*)l, 16, 0, 0);
}

// ---------------------------------------------------------------------------
// f32 -> bf16 conversion (vectorized, 4 elems/thread)
// ---------------------------------------------------------------------------
__global__ __launch_bounds__(256) void cvt_f32_bf16(
    const float* __restrict__ in, __hip_bfloat16* __restrict__ out, size_t n)
{
  const size_t i = ((size_t)blockIdx.x * 256 + threadIdx.x) * 4;
  if (i < n) {
    const float4 v = *(const float4*)(in + i);
    __hip_bfloat16 o0 = __float2bfloat16(v.x);
    __hip_bfloat16 o1 = __float2bfloat16(v.y);
    __hip_bfloat16 o2 = __float2bfloat16(v.z);
    __hip_bfloat16 o3 = __float2bfloat16(v.w);
    ushort4 pk;
    pk.x = *(unsigned short*)&o0; pk.y = *(unsigned short*)&o1;
    pk.z = *(unsigned short*)&o2; pk.w = *(unsigned short*)&o3;
    *(ushort4*)(out + i) = pk;
  }
}

// ---------------------------------------------------------------------------
// mask bit-pack: int32 [2,2048,2048] -> u64 bitmask [2,2048,32]
// ---------------------------------------------------------------------------
__global__ __launch_bounds__(256) void pack_mask(
    const int* __restrict__ mk, unsigned long long* __restrict__ mp)
{
  const size_t gid = (size_t)blockIdx.x * 256 + threadIdx.x;
  const unsigned long long b = __ballot(mk[gid] != 0);
  if ((threadIdx.x & 63) == 0) mp[gid >> 6] = b;
}

// ===========================================================================
// 256x256 8-phase GEMM template (m201 structure): BK=64, 8 waves (2Mx4N),
// acc[8][4] per wave (128x64 output). LDS 128 KiB: A/B double-buffered K-tiles.
// Per K-tile 4 phases; each phase: {ds-read frags | stage 1 half-tile of t+1
// -> s_barrier -> lgkmcnt(0) -> setprio(1) -> 16 MFMA -> setprio(0) ->
// counted vmcnt -> s_barrier}. Stage order Ah0,Bh0,Bh1,Ah1; tails
// vmcnt(4)/vmcnt(4)/none/vmcnt(4) (ledger-verified); last tile drains 4->2->0.
// Chunk-XOR swizzle (phys_chunk = logical ^ (row&7)) via pre-swizzled global
// source (linear gload_lds dest) + same XOR on ds_read: conflict-free b128.
// Row mapping row = i*32 + wm*16 (+ln) makes phase->half deps exact:
// P0(i0-3,j0-1)=Ah0,Bh0  P1(i0-3,j2-3)=Bh1  P2(i4-7,j0-1)=Ah1  P3(i4-7,j2-3).
// ===========================================================================

#define VM4 asm volatile("s_waitcnt vmcnt(4)" ::: "memory")
#define VM2 asm volatile("s_waitcnt vmcnt(2)" ::: "memory")
#define VM0 asm volatile("s_waitcnt vmcnt(0)" ::: "memory")

// PHASE: LOADA=1 reloads A-frags (phases with new qi); B-frags reloaded always.
#define PHASE(qi, qj, LOADA, STAGE, TAILVM)                                     \
  {                                                                             \
    if (LOADA) {                                                                \
      _Pragma("unroll")                                                         \
      for (int ii = 0; ii < 4; ++ii) {                                          \
        af[ii][0] = *(const bf16x8*)(lds + pb * 16384 +                         \
                     (((qi) * 4 + ii) * 32 + arow) * 64 + ((quad) ^ axor) * 8); \
        af[ii][1] = *(const bf16x8*)(lds + pb * 16384 +                         \
                     (((qi) * 4 + ii) * 32 + arow) * 64 + ((4 + quad) ^ axor) * 8); \
      }                                                                         \
    }                                                                           \
    bf16x8 bq[2][2];                                                            \
    _Pragma("unroll")                                                           \
    for (int jj = 0; jj < 2; ++jj) {                                            \
      bq[jj][0] = *(const bf16x8*)(lds + 32768 + pb * 16384 +                   \
                   (((qj) * 2 + jj) * 64 + brow) * 64 + ((quad) ^ axor) * 8);   \
      bq[jj][1] = *(const bf16x8*)(lds + 32768 + pb * 16384 +                   \
                   (((qj) * 2 + jj) * 64 + brow) * 64 + ((4 + quad) ^ axor) * 8); \
    }                                                                           \
    STAGE;                                                                      \
    __builtin_amdgcn_s_barrier();                                               \
    asm volatile("s_waitcnt lgkmcnt(0)" ::: "memory");                          \
    __builtin_amdgcn_sched_barrier(0);                                          \
    __builtin_amdgcn_s_setprio(1);                                              \
    _Pragma("unroll")                                                           \
    for (int ii = 0; ii < 4; ++ii)                                              \
      _Pragma("unroll")                                                         \
      for (int jj = 0; jj < 2; ++jj) {                                          \
        acc[(qi) * 4 + ii][(qj) * 2 + jj] =                                     \
            __builtin_amdgcn_mfma_f32_16x16x32_bf16(                            \
                af[ii][0], bq[jj][0], acc[(qi) * 4 + ii][(qj) * 2 + jj], 0, 0, 0); \
        acc[(qi) * 4 + ii][(qj) * 2 + jj] =                                     \
            __builtin_amdgcn_mfma_f32_16x16x32_bf16(                            \
                af[ii][1], bq[jj][1], acc[(qi) * 4 + ii][(qj) * 2 + jj], 0, 0, 0); \
      }                                                                         \
    __builtin_amdgcn_s_setprio(0);                                              \
    TAILVM;                                                                     \
    __builtin_amdgcn_s_barrier();                                               \
  }

// ---------------------------------------------------------------------------
// QKV GEMM (8-phase 256^2): C[4096,12288] = hidden @ qkv_w^T + qkv_b,
// scattered to Qb/Kb/Vt.
// ---------------------------------------------------------------------------
__global__ __launch_bounds__(512, 2) void qkv_gemm(
    const __hip_bfloat16* __restrict__ A,     // [4096, 4096] bf16
    const __hip_bfloat16* __restrict__ W,     // [12288, 4096] bf16
    const float* __restrict__ bias,           // [12288] f32
    __hip_bfloat16* __restrict__ Qb,
    __hip_bfloat16* __restrict__ Kb,
    __hip_bfloat16* __restrict__ Vt)
{
  __shared__ __align__(16) __hip_bfloat16 lds[65536];  // 128 KiB: A dbuf | B dbuf

  // XCD-bijective swizzle: nwg=768, 768%8==0, chunks of 96
  const int wg  = blockIdx.x;
  const int swz = (wg & 7) * 96 + (wg >> 3);
  const int bx  = swz % 48, by = swz / 48;
  const int m0 = by * 256, n0 = bx * 256;

  const int t = threadIdx.x;
  const int w = t >> 6, l = t & 63;
  const int wm = w >> 2, wn = w & 3;
  const int quad = l >> 4, ln = l & 15;
  const int axor = ln & 7;
  const int arow = wm * 16 + ln;   // + i*32
  const int brow = wn * 16 + ln;   // + j*64
  const int srow8 = l >> 3;
  const int sch   = (l & 7) ^ srow8;   // pre-swizzled source chunk
  char* ldsB = (char*)lds;

  floatx4 acc[8][4] = {};
  bf16x8 af[4][2];

#define STG_A(pbn, h, ktn)                                                      \
  { _Pragma("unroll")                                                           \
    for (int c = 0; c < 2; ++c)                                                 \
      gload16(A + (size_t)(m0 + (h) * 128 + (c * 8 + w) * 8 + srow8) * 4096 +   \
                  (ktn) * 64 + sch * 8,                                         \
              ldsB + (pbn) * 32768 + (h) * 16384 + (c * 8 + w) * 1024);         \
    __builtin_amdgcn_sched_barrier(0); }
#define STG_B(pbn, h, ktn)                                                      \
  { _Pragma("unroll")                                                           \
    for (int c = 0; c < 2; ++c)                                                 \
      gload16(W + (size_t)(n0 + (h) * 128 + (c * 8 + w) * 8 + srow8) * 4096 +   \
                  (ktn) * 64 + sch * 8,                                         \
              ldsB + 65536 + (pbn) * 32768 + (h) * 16384 + (c * 8 + w) * 1024); \
    __builtin_amdgcn_sched_barrier(0); }

  // prologue: tile 0, issue order Ah0,Bh0,Bh1,Ah1; drain to 4 (Ah0,Bh0 landed)
  STG_A(0, 0, 0); STG_B(0, 0, 0); STG_B(0, 1, 0); STG_A(0, 1, 0);
  VM4;
  __builtin_amdgcn_s_barrier();

  int pb = 0;
  for (int kt = 0; kt < 64; ++kt, pb ^= 1) {
    const int ktn = kt + 1;
    const int pbn = pb ^ 1;
    if (ktn < 64) {
      PHASE(0, 0, 1, STG_A(pbn, 0, ktn), VM4)
      PHASE(0, 1, 0, STG_B(pbn, 0, ktn), VM4)
      PHASE(1, 0, 1, STG_B(pbn, 1, ktn), )
      PHASE(1, 1, 0, STG_A(pbn, 1, ktn), VM4)
    } else {   // last tile: no prefetch; drain 4->2->0
      PHASE(0, 0, 1, , VM2)
      PHASE(0, 1, 0, , VM0)
      PHASE(1, 0, 1, , )
      PHASE(1, 1, 0, , )
    }
  }
#undef STG_A
#undef STG_B

  // epilogue: n -> (nh, which, hd); m -> (b, s)
#pragma unroll
  for (int i = 0; i < 8; ++i) {
#pragma unroll
    for (int j = 0; j < 4; ++j) {
      const int n     = n0 + j * 64 + wn * 16 + ln;
      const int nh    = n / 384;
      const int which = (n >> 7) % 3;
      const int hd    = n & 127;
      const float bv  = bias[n];
#pragma unroll
      for (int r = 0; r < 4; ++r) {
        const int m  = m0 + i * 32 + wm * 16 + quad * 4 + r;
        const int bb = m >> 11;
        const int s  = m & 2047;
        const int head = bb * NHEAD + nh;
        const __hip_bfloat16 hv = __float2bfloat16(acc[i][j][r] + bv);
        if (which == 0)      Qb[((size_t)head * S_LEN + s) * HDIM + hd] = hv;
        else if (which == 1) Kb[((size_t)head * S_LEN + s) * HDIM + hd] = hv;
        else                 Vt[((size_t)head * HDIM + hd) * S_LEN + s] = hv;
      }
    }
  }
}

// ---------------------------------------------------------------------------
// Dense GEMM (8-phase 256^2): out[4096,4096] = ctx @ dense_w^T + b + residual.
// ctx is head-major in the Q region: (b,s,nh,hd) at ((b*32+nh)*2048+s)*128+hd.
// 64-wide k-tiles never cross a head boundary (4096%... kt*64: hd0 in {0,64}).
// ---------------------------------------------------------------------------
__global__ __launch_bounds__(512, 2) void dense_gemm(
    const __hip_bfloat16* __restrict__ CtxQ,   // head-major ctx (Q region)
    const __hip_bfloat16* __restrict__ W,      // [4096, 4096] bf16
    const float* __restrict__ bias,            // [4096] f32
    const float* __restrict__ residual,        // [4096, 4096] f32
    float* __restrict__ out)                   // [4096, 4096] f32
{
  __shared__ __align__(16) __hip_bfloat16 lds[65536];  // 128 KiB

  // XCD-bijective swizzle: nwg=256, chunks of 32
  const int wg  = blockIdx.x;
  const int swz = (wg & 7) * 32 + (wg >> 3);
  const int bx  = swz & 15, by = swz >> 4;
  const int m0 = by * 256, n0 = bx * 256;

  const int t = threadIdx.x;
  const int w = t >> 6, l = t & 63;
  const int wm = w >> 2, wn = w & 3;
  const int quad = l >> 4, ln = l & 15;
  const int axor = ln & 7;
  const int arow = wm * 16 + ln;
  const int brow = wn * 16 + ln;
  const int srow8 = l >> 3;
  const int sch   = (l & 7) ^ srow8;
  char* ldsB = (char*)lds;

  floatx4 acc[8][4] = {};
  bf16x8 af[4][2];

#define STG_A(pbn, h, ktn)                                                      \
  { const int nh_ = (ktn) >> 1;                                                 \
    const int hd_ = ((ktn) & 1) * 64 + sch * 8;                                 \
    _Pragma("unroll")                                                           \
    for (int c = 0; c < 2; ++c) {                                               \
      const int m_ = m0 + (h) * 128 + (c * 8 + w) * 8 + srow8;                  \
      gload16(CtxQ + ((size_t)(((m_ >> 11) * NHEAD + nh_) * S_LEN + (m_ & 2047))) * HDIM + hd_, \
              ldsB + (pbn) * 32768 + (h) * 16384 + (c * 8 + w) * 1024); }       \
    __builtin_amdgcn_sched_barrier(0); }
#define STG_B(pbn, h, ktn)                                                      \
  { _Pragma("unroll")                                                           \
    for (int c = 0; c < 2; ++c)                                                 \
      gload16(W + (size_t)(n0 + (h) * 128 + (c * 8 + w) * 8 + srow8) * 4096 +   \
                  (ktn) * 64 + sch * 8,                                         \
              ldsB + 65536 + (pbn) * 32768 + (h) * 16384 + (c * 8 + w) * 1024); \
    __builtin_amdgcn_sched_barrier(0); }

  STG_A(0, 0, 0); STG_B(0, 0, 0); STG_B(0, 1, 0); STG_A(0, 1, 0);
  VM4;
  __builtin_amdgcn_s_barrier();

  int pb = 0;
  for (int kt = 0; kt < 64; ++kt, pb ^= 1) {
    const int ktn = kt + 1;
    const int pbn = pb ^ 1;
    if (ktn < 64) {
      PHASE(0, 0, 1, STG_A(pbn, 0, ktn), VM4)
      PHASE(0, 1, 0, STG_B(pbn, 0, ktn), VM4)
      PHASE(1, 0, 1, STG_B(pbn, 1, ktn), )
      PHASE(1, 1, 0, STG_A(pbn, 1, ktn), VM4)
    } else {
      PHASE(0, 0, 1, , VM2)
      PHASE(0, 1, 0, , VM0)
      PHASE(1, 0, 1, , )
      PHASE(1, 1, 0, , )
    }
  }
#undef STG_A
#undef STG_B

#pragma unroll
  for (int i = 0; i < 8; ++i) {
#pragma unroll
    for (int j = 0; j < 4; ++j) {
      const int n = n0 + j * 64 + wn * 16 + ln;
      const float bv = bias[n];
#pragma unroll
      for (int r = 0; r < 4; ++r) {
        const int m = m0 + i * 32 + wm * 16 + quad * 4 + r;
        out[(size_t)m * HSZ + n] =
            acc[i][j][r] + bv + residual[(size_t)m * HSZ + n];
      }
    }
  }
}

// ---------------------------------------------------------------------------
// Flash attention (unchanged from R2). One block per (head, 64 q-rows);
// 4 waves x 16 q-rows. KVBLK=64, LDS-staged K/V (dbuf, gload_lds, XOR swizzle),
// log2-domain softmax, bit-packed mask. O overwrites Q region in place.
// ---------------------------------------------------------------------------
__global__ __launch_bounds__(256) void flash_attn(
    __hip_bfloat16* __restrict__ Qb,           // [64, 2048, 128] in, O out
    const __hip_bfloat16* __restrict__ Kb,     // [64, 2048, 128]
    const __hip_bfloat16* __restrict__ Vt,     // [64, 128, 2048]
    const float* __restrict__ alibi,           // [64, 2048] f32
    const unsigned long long* __restrict__ mpack)  // [2, 2048, 32] u64 bitmask
{
  __shared__ __align__(16) __hip_bfloat16 KsS[2][64 * 128];
  __shared__ __align__(16) __hip_bfloat16 VsS[2][128 * 64];
  __shared__ __align__(16) __hip_bfloat16 Psh[4][16 * 72];

  const int head = blockIdx.x >> 5;
  const int qblk = blockIdx.x & 31;
  const int t = threadIdx.x;
  const int w = t >> 6, l = t & 63;
  const int quad = l >> 4, ln = l & 15;
  const int b = head >> 5;
  const int q0 = qblk * 64 + w * 16;

  __hip_bfloat16* Qh = Qb + (size_t)head * S_LEN * HDIM;
  const __hip_bfloat16* Kh = Kb + (size_t)head * S_LEN * HDIM;
  const __hip_bfloat16* Vh = Vt + (size_t)head * HDIM * S_LEN;
  const float* al = alibi + (size_t)head * S_LEN;
  const unsigned long long* mkp = mpack + (size_t)b * S_LEN * (S_LEN / 64);

#define STAGE_KV(kj, Ks, Vs)                                                   \
  {                                                                            \
    _Pragma("unroll")                                                          \
    for (int c = 0; c < 4; ++c) {                                              \
      const int s   = (w * 4 + c) * 64 + l;                                    \
      const int row = s >> 4, ch = s & 15;                                     \
      const int g   = ch ^ (row & 7);                                          \
      gload16(Kh + (size_t)((kj) + row) * HDIM + g * 8,                        \
              (char*)(Ks) + (w * 4 + c) * 1024);                               \
    }                                                                          \
    _Pragma("unroll")                                                          \
    for (int c = 0; c < 4; ++c) {                                              \
      const int s   = (w * 4 + c) * 64 + l;                                    \
      const int row = s >> 3, ch = s & 7;                                      \
      const int g   = ch ^ (row & 7);                                          \
      gload16(Vh + (size_t)row * S_LEN + (kj) + g * 8,                         \
              (char*)(Vs) + (w * 4 + c) * 1024);                               \
    }                                                                          \
  }

  STAGE_KV(0, KsS[0], VsS[0]);

  bf16x8 qf[4];
#pragma unroll
  for (int ks = 0; ks < 4; ++ks)
    qf[ks] = *(const bf16x8*)(Qh + (size_t)(q0 + ln) * HDIM + ks * 32 + quad * 8);

  float m_run[4], lpart[4], alp[4], sv[4][4];
  floatx4 accO[8] = {};
#pragma unroll
  for (int r = 0; r < 4; ++r) { m_run[r] = -INFINITY; lpart[r] = 0.f; }

  __hip_bfloat16* Pw = Psh[w];
  const float SC = INV_NORM * LOG2E;
  const int ln7 = ln & 7;

  __syncthreads();

  for (int kj0 = 0, it = 0; kj0 < S_LEN; kj0 += 64, ++it) {
    const int cur = it & 1;
    const __hip_bfloat16* Kc = KsS[cur];
    const __hip_bfloat16* Vc = VsS[cur];

    if (kj0 + 64 < S_LEN) STAGE_KV(kj0 + 64, KsS[cur ^ 1], VsS[cur ^ 1]);

    unsigned long long mb[4];
#pragma unroll
    for (int r = 0; r < 4; ++r)
      mb[r] = mkp[(size_t)(q0 + quad * 4 + r) * (S_LEN / 64) + (kj0 >> 6)];
    float av[4];
#pragma unroll
    for (int tt = 0; tt < 4; ++tt)
      av[tt] = al[kj0 + tt * 16 + ln] * LOG2E;

#pragma unroll
    for (int tt = 0; tt < 4; ++tt) {
      floatx4 accS = {};
#pragma unroll
      for (int ks = 0; ks < 4; ++ks) {
        const int row = tt * 16 + ln;
        const int c   = (ks * 4 + quad) ^ ln7;
        bf16x8 kf = *(const bf16x8*)(Kc + row * 128 + c * 8);
        accS = __builtin_amdgcn_mfma_f32_16x16x32_bf16(qf[ks], kf, accS, 0, 0, 0);
      }
#pragma unroll
      for (int r = 0; r < 4; ++r) {
        float s = accS[r] * SC + av[tt];
        if ((mb[r] >> (tt * 16 + ln)) & 1ull) s = NEG_MIN;
        sv[tt][r] = s;
      }
    }

    bool resc = false;
#pragma unroll
    for (int r = 0; r < 4; ++r) {
      float cm = fmaxf(fmaxf(sv[0][r], sv[1][r]), fmaxf(sv[2][r], sv[3][r]));
      cm = fmaxf(cm, __shfl_xor(cm, 1, 64));
      cm = fmaxf(cm, __shfl_xor(cm, 2, 64));
      cm = fmaxf(cm, __shfl_xor(cm, 4, 64));
      cm = fmaxf(cm, __shfl_xor(cm, 8, 64));
      const float mn = fmaxf(m_run[r], cm);
      const float a  = __builtin_amdgcn_exp2f(m_run[r] - mn);
      alp[r] = a;
      if (a != 1.f) resc = true;
      m_run[r] = mn;
      float ps = 0.f;
#pragma unroll
      for (int tt = 0; tt < 4; ++tt) {
        const float p = __builtin_amdgcn_exp2f(sv[tt][r] - mn);
        sv[tt][r] = p;
        ps += p;
      }
      lpart[r] = lpart[r] * a + ps;
    }
    if (__any(resc)) {
#pragma unroll
      for (int dt = 0; dt < 8; ++dt)
#pragma unroll
        for (int r = 0; r < 4; ++r) accO[dt][r] *= alp[r];
    }

#pragma unroll
    for (int tt = 0; tt < 4; ++tt)
#pragma unroll
      for (int r = 0; r < 4; ++r)
        Pw[(quad * 4 + r) * 72 + tt * 16 + ln] = __float2bfloat16(sv[tt][r]);
    __builtin_amdgcn_wave_barrier();
    const bf16x8 pf0 = *(const bf16x8*)(Pw + ln * 72 + quad * 8);
    const bf16x8 pf1 = *(const bf16x8*)(Pw + ln * 72 + 32 + quad * 8);

#pragma unroll
    for (int dt = 0; dt < 8; ++dt) {
      const int row = dt * 16 + ln;
      const int c0  = quad ^ ln7;
      const int c1  = (4 + quad) ^ ln7;
      bf16x8 vf0 = *(const bf16x8*)(Vc + row * 64 + c0 * 8);
      bf16x8 vf1 = *(const bf16x8*)(Vc + row * 64 + c1 * 8);
      accO[dt] = __builtin_amdgcn_mfma_f32_16x16x32_bf16(pf0, vf0, accO[dt], 0, 0, 0);
      accO[dt] = __builtin_amdgcn_mfma_f32_16x16x32_bf16(pf1, vf1, accO[dt], 0, 0, 0);
    }
    __builtin_amdgcn_wave_barrier();

    __syncthreads();
  }
#undef STAGE_KV

#pragma unroll
  for (int r = 0; r < 4; ++r) {
    float ps = lpart[r];
    ps += __shfl_xor(ps, 1, 64);
    ps += __shfl_xor(ps, 2, 64);
    ps += __shfl_xor(ps, 4, 64);
    ps += __shfl_xor(ps, 8, 64);
    const int qi = q0 + quad * 4 + r;
    const float invl = 1.0f / ps;
#pragma unroll
    for (int dt = 0; dt < 8; ++dt)
      Qh[(size_t)qi * HDIM + dt * 16 + ln] = __float2bfloat16(accO[dt][r] * invl);
  }
}

extern "C" void kernel_launch(void* const* d_in, const int* in_sizes, int n_in,
                              void* d_out, int out_size, void* d_ws, size_t ws_size,
                              hipStream_t stream) {
  const float* hidden   = (const float*)d_in[0];
  const float* residual = (const float*)d_in[1];
  const float* alibi    = (const float*)d_in[2];
  const int*   mask     = (const int*)d_in[3];
  const float* qkv_w    = (const float*)d_in[4];
  const float* qkv_b    = (const float*)d_in[5];
  const float* dense_w  = (const float*)d_in[6];
  const float* dense_b  = (const float*)d_in[7];
  float* out = (float*)d_out;   // reference output dtype is float32

  const size_t per  = (size_t)NH_TOT * S_LEN * HDIM;  // 16,777,216 elems
  const size_t nWq  = (size_t)3 * HSZ * HSZ;          // 50,331,648 elems
  __hip_bfloat16* Qb = (__hip_bfloat16*)d_ws;
  __hip_bfloat16* Kb = Qb + per;
  __hip_bfloat16* Vt = Kb + per;
  __hip_bfloat16* Ah = Vt + per;        // hidden bf16, later reused for dense_w
  __hip_bfloat16* Wq = Ah + per;        // qkv_w bf16; later reused for mask bits
  unsigned long long* mp = (unsigned long long*)Wq;   // 1 MB, after qkv_gemm

  // convert f32 inputs to bf16
  cvt_f32_bf16<<<(int)(per / 4 / 256), 256, 0, stream>>>(hidden, Ah, per);
  cvt_f32_bf16<<<(int)(nWq / 4 / 256), 256, 0, stream>>>(qkv_w, Wq, nWq);

  qkv_gemm<<<dim3(768), 512, 0, stream>>>(Ah, Wq, qkv_b, Qb, Kb, Vt);

  // Wq dead now -> pack mask bits there; Ah dead -> reuse for dense_w bf16
  pack_mask<<<(int)(2u * S_LEN * S_LEN / 256), 256, 0, stream>>>(mask, mp);
  cvt_f32_bf16<<<(int)(per / 4 / 256), 256, 0, stream>>>(dense_w, Ah, per);

  flash_attn<<<dim3(2048), 256, 0, stream>>>(Qb, Kb, Vt, alibi, mp);
  dense_gemm<<<dim3(256), 512, 0, stream>>>(Qb, Ah, dense_b, residual, out);
}

// Round 4
// 1184.164 us; speedup vs baseline: 1.9148x; 1.0879x over previous
//
#include <hip/hip_runtime.h>
#include <hip/hip_bf16.h>

// Problem constants
#define S_LEN 2048
#define NHEAD 32     // heads per batch
#define HDIM  128
#define HSZ   4096
#define NH_TOT 64    // B * NH
#define INV_NORM 0.08838834764831845f       // 1/sqrt(128)
#define NEG_MIN  -3.4028234663852886e38f    // finfo(float32).min
#define LOG2E    1.4426950408889634f

typedef __attribute__((ext_vector_type(8))) __bf16 bf16x8;
typedef __attribute__((ext_vector_type(4))) float  floatx4;

// async 16B global->LDS. lds ptr must be wave-uniform; HW scatters lane i to base + i*16.
__device__ __forceinline__ void gload16(const void* g, void* l) {
  __builtin_amdgcn_global_load_lds(
      (__attribute__((address_space(1))) void*)g,
      (__attribute__((address_space(3))) void*)l, 16, 0, 0);
}

// ---------------------------------------------------------------------------
// f32 -> bf16 conversion (vectorized, 4 elems/thread)
// ---------------------------------------------------------------------------
__global__ __launch_bounds__(256) void cvt_f32_bf16(
    const float* __restrict__ in, __hip_bfloat16* __restrict__ out, size_t n)
{
  const size_t i = ((size_t)blockIdx.x * 256 + threadIdx.x) * 4;
  if (i < n) {
    const float4 v = *(const float4*)(in + i);
    __hip_bfloat16 o0 = __float2bfloat16(v.x);
    __hip_bfloat16 o1 = __float2bfloat16(v.y);
    __hip_bfloat16 o2 = __float2bfloat16(v.z);
    __hip_bfloat16 o3 = __float2bfloat16(v.w);
    ushort4 pk;
    pk.x = *(unsigned short*)&o0; pk.y = *(unsigned short*)&o1;
    pk.z = *(unsigned short*)&o2; pk.w = *(unsigned short*)&o3;
    *(ushort4*)(out + i) = pk;
  }
}

// ---------------------------------------------------------------------------
// mask bit-pack: int32 [2,2048,2048] -> u64 bitmask [2,2048,32]
// ---------------------------------------------------------------------------
__global__ __launch_bounds__(256) void pack_mask(
    const int* __restrict__ mk, unsigned long long* __restrict__ mp)
{
  const size_t gid = (size_t)blockIdx.x * 256 + threadIdx.x;
  const unsigned long long b = __ballot(mk[gid] != 0);
  if ((threadIdx.x & 63) == 0) mp[gid >> 6] = b;
}

// ===========================================================================
// 256x256 8-phase GEMM template (m201 structure) — unchanged from R3.
// ===========================================================================

#define VM4 asm volatile("s_waitcnt vmcnt(4)" ::: "memory")
#define VM2 asm volatile("s_waitcnt vmcnt(2)" ::: "memory")
#define VM0 asm volatile("s_waitcnt vmcnt(0)" ::: "memory")

#define PHASE(qi, qj, LOADA, STAGE, TAILVM)                                     \
  {                                                                             \
    if (LOADA) {                                                                \
      _Pragma("unroll")                                                         \
      for (int ii = 0; ii < 4; ++ii) {                                          \
        af[ii][0] = *(const bf16x8*)(lds + pb * 16384 +                         \
                     (((qi) * 4 + ii) * 32 + arow) * 64 + ((quad) ^ axor) * 8); \
        af[ii][1] = *(const bf16x8*)(lds + pb * 16384 +                         \
                     (((qi) * 4 + ii) * 32 + arow) * 64 + ((4 + quad) ^ axor) * 8); \
      }                                                                         \
    }                                                                           \
    bf16x8 bq[2][2];                                                            \
    _Pragma("unroll")                                                           \
    for (int jj = 0; jj < 2; ++jj) {                                            \
      bq[jj][0] = *(const bf16x8*)(lds + 32768 + pb * 16384 +                   \
                   (((qj) * 2 + jj) * 64 + brow) * 64 + ((quad) ^ axor) * 8);   \
      bq[jj][1] = *(const bf16x8*)(lds + 32768 + pb * 16384 +                   \
                   (((qj) * 2 + jj) * 64 + brow) * 64 + ((4 + quad) ^ axor) * 8); \
    }                                                                           \
    STAGE;                                                                      \
    __builtin_amdgcn_s_barrier();                                               \
    asm volatile("s_waitcnt lgkmcnt(0)" ::: "memory");                          \
    __builtin_amdgcn_sched_barrier(0);                                          \
    __builtin_amdgcn_s_setprio(1);                                              \
    _Pragma("unroll")                                                           \
    for (int ii = 0; ii < 4; ++ii)                                              \
      _Pragma("unroll")                                                         \
      for (int jj = 0; jj < 2; ++jj) {                                          \
        acc[(qi) * 4 + ii][(qj) * 2 + jj] =                                     \
            __builtin_amdgcn_mfma_f32_16x16x32_bf16(                            \
                af[ii][0], bq[jj][0], acc[(qi) * 4 + ii][(qj) * 2 + jj], 0, 0, 0); \
        acc[(qi) * 4 + ii][(qj) * 2 + jj] =                                     \
            __builtin_amdgcn_mfma_f32_16x16x32_bf16(                            \
                af[ii][1], bq[jj][1], acc[(qi) * 4 + ii][(qj) * 2 + jj], 0, 0, 0); \
      }                                                                         \
    __builtin_amdgcn_s_setprio(0);                                              \
    TAILVM;                                                                     \
    __builtin_amdgcn_s_barrier();                                               \
  }

// ---------------------------------------------------------------------------
// QKV GEMM (8-phase 256^2): C[4096,12288] = hidden @ qkv_w^T + qkv_b,
// scattered to Qb/Kb/Vt.
// ---------------------------------------------------------------------------
__global__ __launch_bounds__(512, 2) void qkv_gemm(
    const __hip_bfloat16* __restrict__ A,     // [4096, 4096] bf16
    const __hip_bfloat16* __restrict__ W,     // [12288, 4096] bf16
    const float* __restrict__ bias,           // [12288] f32
    __hip_bfloat16* __restrict__ Qb,
    __hip_bfloat16* __restrict__ Kb,
    __hip_bfloat16* __restrict__ Vt)
{
  __shared__ __align__(16) __hip_bfloat16 lds[65536];  // 128 KiB: A dbuf | B dbuf

  const int wg  = blockIdx.x;
  const int swz = (wg & 7) * 96 + (wg >> 3);
  const int bx  = swz % 48, by = swz / 48;
  const int m0 = by * 256, n0 = bx * 256;

  const int t = threadIdx.x;
  const int w = t >> 6, l = t & 63;
  const int wm = w >> 2, wn = w & 3;
  const int quad = l >> 4, ln = l & 15;
  const int axor = ln & 7;
  const int arow = wm * 16 + ln;
  const int brow = wn * 16 + ln;
  const int srow8 = l >> 3;
  const int sch   = (l & 7) ^ srow8;
  char* ldsB = (char*)lds;

  floatx4 acc[8][4] = {};
  bf16x8 af[4][2];

#define STG_A(pbn, h, ktn)                                                      \
  { _Pragma("unroll")                                                           \
    for (int c = 0; c < 2; ++c)                                                 \
      gload16(A + (size_t)(m0 + (h) * 128 + (c * 8 + w) * 8 + srow8) * 4096 +   \
                  (ktn) * 64 + sch * 8,                                         \
              ldsB + (pbn) * 32768 + (h) * 16384 + (c * 8 + w) * 1024);         \
    __builtin_amdgcn_sched_barrier(0); }
#define STG_B(pbn, h, ktn)                                                      \
  { _Pragma("unroll")                                                           \
    for (int c = 0; c < 2; ++c)                                                 \
      gload16(W + (size_t)(n0 + (h) * 128 + (c * 8 + w) * 8 + srow8) * 4096 +   \
                  (ktn) * 64 + sch * 8,                                         \
              ldsB + 65536 + (pbn) * 32768 + (h) * 16384 + (c * 8 + w) * 1024); \
    __builtin_amdgcn_sched_barrier(0); }

  STG_A(0, 0, 0); STG_B(0, 0, 0); STG_B(0, 1, 0); STG_A(0, 1, 0);
  VM4;
  __builtin_amdgcn_s_barrier();

  int pb = 0;
  for (int kt = 0; kt < 64; ++kt, pb ^= 1) {
    const int ktn = kt + 1;
    const int pbn = pb ^ 1;
    if (ktn < 64) {
      PHASE(0, 0, 1, STG_A(pbn, 0, ktn), VM4)
      PHASE(0, 1, 0, STG_B(pbn, 0, ktn), VM4)
      PHASE(1, 0, 1, STG_B(pbn, 1, ktn), )
      PHASE(1, 1, 0, STG_A(pbn, 1, ktn), VM4)
    } else {
      PHASE(0, 0, 1, , VM2)
      PHASE(0, 1, 0, , VM0)
      PHASE(1, 0, 1, , )
      PHASE(1, 1, 0, , )
    }
  }
#undef STG_A
#undef STG_B

#pragma unroll
  for (int i = 0; i < 8; ++i) {
#pragma unroll
    for (int j = 0; j < 4; ++j) {
      const int n     = n0 + j * 64 + wn * 16 + ln;
      const int nh    = n / 384;
      const int which = (n >> 7) % 3;
      const int hd    = n & 127;
      const float bv  = bias[n];
#pragma unroll
      for (int r = 0; r < 4; ++r) {
        const int m  = m0 + i * 32 + wm * 16 + quad * 4 + r;
        const int bb = m >> 11;
        const int s  = m & 2047;
        const int head = bb * NHEAD + nh;
        const __hip_bfloat16 hv = __float2bfloat16(acc[i][j][r] + bv);
        if (which == 0)      Qb[((size_t)head * S_LEN + s) * HDIM + hd] = hv;
        else if (which == 1) Kb[((size_t)head * S_LEN + s) * HDIM + hd] = hv;
        else                 Vt[((size_t)head * HDIM + hd) * S_LEN + s] = hv;
      }
    }
  }
}

// ---------------------------------------------------------------------------
// Dense GEMM (8-phase 256^2): out[4096,4096] = ctx @ dense_w^T + b + residual.
// ---------------------------------------------------------------------------
__global__ __launch_bounds__(512, 2) void dense_gemm(
    const __hip_bfloat16* __restrict__ CtxQ,   // head-major ctx (Q region)
    const __hip_bfloat16* __restrict__ W,      // [4096, 4096] bf16
    const float* __restrict__ bias,            // [4096] f32
    const float* __restrict__ residual,        // [4096, 4096] f32
    float* __restrict__ out)                   // [4096, 4096] f32
{
  __shared__ __align__(16) __hip_bfloat16 lds[65536];  // 128 KiB

  const int wg  = blockIdx.x;
  const int swz = (wg & 7) * 32 + (wg >> 3);
  const int bx  = swz & 15, by = swz >> 4;
  const int m0 = by * 256, n0 = bx * 256;

  const int t = threadIdx.x;
  const int w = t >> 6, l = t & 63;
  const int wm = w >> 2, wn = w & 3;
  const int quad = l >> 4, ln = l & 15;
  const int axor = ln & 7;
  const int arow = wm * 16 + ln;
  const int brow = wn * 16 + ln;
  const int srow8 = l >> 3;
  const int sch   = (l & 7) ^ srow8;
  char* ldsB = (char*)lds;

  floatx4 acc[8][4] = {};
  bf16x8 af[4][2];

#define STG_A(pbn, h, ktn)                                                      \
  { const int nh_ = (ktn) >> 1;                                                 \
    const int hd_ = ((ktn) & 1) * 64 + sch * 8;                                 \
    _Pragma("unroll")                                                           \
    for (int c = 0; c < 2; ++c) {                                               \
      const int m_ = m0 + (h) * 128 + (c * 8 + w) * 8 + srow8;                  \
      gload16(CtxQ + ((size_t)(((m_ >> 11) * NHEAD + nh_) * S_LEN + (m_ & 2047))) * HDIM + hd_, \
              ldsB + (pbn) * 32768 + (h) * 16384 + (c * 8 + w) * 1024); }       \
    __builtin_amdgcn_sched_barrier(0); }
#define STG_B(pbn, h, ktn)                                                      \
  { _Pragma("unroll")                                                           \
    for (int c = 0; c < 2; ++c)                                                 \
      gload16(W + (size_t)(n0 + (h) * 128 + (c * 8 + w) * 8 + srow8) * 4096 +   \
                  (ktn) * 64 + sch * 8,                                         \
              ldsB + 65536 + (pbn) * 32768 + (h) * 16384 + (c * 8 + w) * 1024); \
    __builtin_amdgcn_sched_barrier(0); }

  STG_A(0, 0, 0); STG_B(0, 0, 0); STG_B(0, 1, 0); STG_A(0, 1, 0);
  VM4;
  __builtin_amdgcn_s_barrier();

  int pb = 0;
  for (int kt = 0; kt < 64; ++kt, pb ^= 1) {
    const int ktn = kt + 1;
    const int pbn = pb ^ 1;
    if (ktn < 64) {
      PHASE(0, 0, 1, STG_A(pbn, 0, ktn), VM4)
      PHASE(0, 1, 0, STG_B(pbn, 0, ktn), VM4)
      PHASE(1, 0, 1, STG_B(pbn, 1, ktn), )
      PHASE(1, 1, 0, STG_A(pbn, 1, ktn), VM4)
    } else {
      PHASE(0, 0, 1, , VM2)
      PHASE(0, 1, 0, , VM0)
      PHASE(1, 0, 1, , )
      PHASE(1, 1, 0, , )
    }
  }
#undef STG_A
#undef STG_B

#pragma unroll
  for (int i = 0; i < 8; ++i) {
#pragma unroll
    for (int j = 0; j < 4; ++j) {
      const int n = n0 + j * 64 + wn * 16 + ln;
      const float bv = bias[n];
#pragma unroll
      for (int r = 0; r < 4; ++r) {
        const int m = m0 + i * 32 + wm * 16 + quad * 4 + r;
        out[(size_t)m * HSZ + n] =
            acc[i][j][r] + bv + residual[(size_t)m * HSZ + n];
      }
    }
  }
}

// ---------------------------------------------------------------------------
// Flash attention v2: one block per (head, 128 q-rows); 4 waves x 32 q-rows
// (two 16-row groups per wave). Each kf/vf LDS read feeds BOTH groups' MFMAs
// -> per-q K/V LDS traffic halves vs 16-rows/wave. K double-buffered; V
// single-buffered (staged at iter start, landed by the mid-iter barrier).
// P: per-wave per-group [16][72] buffers (LDS 66 KB total -> 2 blocks/CU).
// Softmax log2-domain, bit-packed mask. O overwrites Q region in place.
// ---------------------------------------------------------------------------
__global__ __launch_bounds__(256, 2) void flash_attn(
    __hip_bfloat16* __restrict__ Qb,           // [64, 2048, 128] in, O out
    const __hip_bfloat16* __restrict__ Kb,     // [64, 2048, 128]
    const __hip_bfloat16* __restrict__ Vt,     // [64, 128, 2048]
    const float* __restrict__ alibi,           // [64, 2048] f32
    const unsigned long long* __restrict__ mpack)  // [2, 2048, 32] u64 bitmask
{
  __shared__ __align__(16) __hip_bfloat16 KsS[2][64 * 128];   // 32 KB (dbuf)
  __shared__ __align__(16) __hip_bfloat16 Vs[128 * 64];       // 16 KB (single)
  __shared__ __align__(16) __hip_bfloat16 Psh[4][2][16 * 72]; // 18 KB

  const int head = blockIdx.x >> 4;
  const int qblk = blockIdx.x & 15;
  const int t = threadIdx.x;
  const int w = t >> 6, l = t & 63;
  const int quad = l >> 4, ln = l & 15;
  const int b = head >> 5;
  const int q0 = qblk * 128 + w * 32;   // wave's 32 rows: q0 + g*16 + (0..15)

  __hip_bfloat16* Qh = Qb + (size_t)head * S_LEN * HDIM;
  const __hip_bfloat16* Kh = Kb + (size_t)head * S_LEN * HDIM;
  const __hip_bfloat16* Vh = Vt + (size_t)head * HDIM * S_LEN;
  const float* al = alibi + (size_t)head * S_LEN;
  const unsigned long long* mkp = mpack + (size_t)b * S_LEN * (S_LEN / 64);

#define STAGE_K(kj, Ks)                                                        \
  { _Pragma("unroll")                                                          \
    for (int c = 0; c < 4; ++c) {                                              \
      const int s   = (w * 4 + c) * 64 + l;                                    \
      const int row = s >> 4, ch = s & 15;                                     \
      const int g   = ch ^ (row & 7);                                          \
      gload16(Kh + (size_t)((kj) + row) * HDIM + g * 8,                        \
              (char*)(Ks) + (w * 4 + c) * 1024);                               \
    } }
#define STAGE_V(kj)                                                            \
  { _Pragma("unroll")                                                          \
    for (int c = 0; c < 4; ++c) {                                              \
      const int s   = (w * 4 + c) * 64 + l;                                    \
      const int row = s >> 3, ch = s & 7;                                      \
      const int g   = ch ^ (row & 7);                                          \
      gload16(Vh + (size_t)row * S_LEN + (kj) + g * 8,                         \
              (char*)(Vs) + (w * 4 + c) * 1024);                               \
    } }

  // prologue: stage K(0); Q fragments load in the shadow
  STAGE_K(0, KsS[0]);

  bf16x8 qf[2][4];
#pragma unroll
  for (int g = 0; g < 2; ++g)
#pragma unroll
    for (int ks = 0; ks < 4; ++ks)
      qf[g][ks] = *(const bf16x8*)(Qh + (size_t)(q0 + g * 16 + ln) * HDIM + ks * 32 + quad * 8);

  float m_run[2][4], lpart[2][4], alp[2][4], sv[2][4][4];
  floatx4 accO[2][8] = {};
#pragma unroll
  for (int g = 0; g < 2; ++g)
#pragma unroll
    for (int r = 0; r < 4; ++r) { m_run[g][r] = -INFINITY; lpart[g][r] = 0.f; }

  const float SC = INV_NORM * LOG2E;
  const int ln7 = ln & 7;

  __syncthreads();   // K(0) staged

  for (int kj0 = 0, it = 0; kj0 < S_LEN; kj0 += 64, ++it) {
    const int cur = it & 1;
    const __hip_bfloat16* Kc = KsS[cur];

    // stage V(t) (needed after mid-iter barrier) and prefetch K(t+1)
    STAGE_V(kj0);
    if (kj0 + 64 < S_LEN) STAGE_K(kj0 + 64, KsS[cur ^ 1]);

    // mask bits + alibi (alibi is q-independent: shared across groups)
    unsigned long long mb[2][4];
#pragma unroll
    for (int g = 0; g < 2; ++g)
#pragma unroll
      for (int r = 0; r < 4; ++r)
        mb[g][r] = mkp[(size_t)(q0 + g * 16 + quad * 4 + r) * (S_LEN / 64) + (kj0 >> 6)];
    float av[4];
#pragma unroll
    for (int tt = 0; tt < 4; ++tt)
      av[tt] = al[kj0 + tt * 16 + ln] * LOG2E;

    // scores: each kf read feeds both groups
#pragma unroll
    for (int tt = 0; tt < 4; ++tt) {
      floatx4 accS0 = {}, accS1 = {};
#pragma unroll
      for (int ks = 0; ks < 4; ++ks) {
        const int row = tt * 16 + ln;
        const int c   = (ks * 4 + quad) ^ ln7;
        bf16x8 kf = *(const bf16x8*)(Kc + row * 128 + c * 8);
        accS0 = __builtin_amdgcn_mfma_f32_16x16x32_bf16(qf[0][ks], kf, accS0, 0, 0, 0);
        accS1 = __builtin_amdgcn_mfma_f32_16x16x32_bf16(qf[1][ks], kf, accS1, 0, 0, 0);
      }
#pragma unroll
      for (int r = 0; r < 4; ++r) {
        float s0 = accS0[r] * SC + av[tt];
        float s1 = accS1[r] * SC + av[tt];
        if ((mb[0][r] >> (tt * 16 + ln)) & 1ull) s0 = NEG_MIN;
        if ((mb[1][r] >> (tt * 16 + ln)) & 1ull) s1 = NEG_MIN;
        sv[0][tt][r] = s0;
        sv[1][tt][r] = s1;
      }
    }

    // online softmax, log2 domain
    bool resc = false;
#pragma unroll
    for (int g = 0; g < 2; ++g)
#pragma unroll
    for (int r = 0; r < 4; ++r) {
      float cm = fmaxf(fmaxf(sv[g][0][r], sv[g][1][r]), fmaxf(sv[g][2][r], sv[g][3][r]));
      cm = fmaxf(cm, __shfl_xor(cm, 1, 64));
      cm = fmaxf(cm, __shfl_xor(cm, 2, 64));
      cm = fmaxf(cm, __shfl_xor(cm, 4, 64));
      cm = fmaxf(cm, __shfl_xor(cm, 8, 64));
      const float mn = fmaxf(m_run[g][r], cm);
      const float a  = __builtin_amdgcn_exp2f(m_run[g][r] - mn);
      alp[g][r] = a;
      if (a != 1.f) resc = true;
      m_run[g][r] = mn;
      float ps = 0.f;
#pragma unroll
      for (int tt = 0; tt < 4; ++tt) {
        const float p = __builtin_amdgcn_exp2f(sv[g][tt][r] - mn);
        sv[g][tt][r] = p;
        ps += p;
      }
      lpart[g][r] = lpart[g][r] * a + ps;
    }
    if (__any(resc)) {
#pragma unroll
      for (int g = 0; g < 2; ++g)
#pragma unroll
        for (int dt = 0; dt < 8; ++dt)
#pragma unroll
          for (int r = 0; r < 4; ++r) accO[g][dt][r] *= alp[g][r];
    }

    // P -> LDS (per-wave per-group buffers)
#pragma unroll
    for (int g = 0; g < 2; ++g)
#pragma unroll
      for (int tt = 0; tt < 4; ++tt)
#pragma unroll
        for (int r = 0; r < 4; ++r)
          Psh[w][g][(quad * 4 + r) * 72 + tt * 16 + ln] = __float2bfloat16(sv[g][tt][r]);

    __syncthreads();   // V(t) (and K(t+1)) landed; own P writes complete

    bf16x8 pfr[2][2];
#pragma unroll
    for (int g = 0; g < 2; ++g) {
      pfr[g][0] = *(const bf16x8*)(&Psh[w][g][0] + ln * 72 + quad * 8);
      pfr[g][1] = *(const bf16x8*)(&Psh[w][g][0] + ln * 72 + 32 + quad * 8);
    }

    // PV: each vf read feeds both groups
#pragma unroll
    for (int dt = 0; dt < 8; ++dt) {
      const int row = dt * 16 + ln;
      const int c0  = quad ^ ln7;
      const int c1  = (4 + quad) ^ ln7;
      bf16x8 vf0 = *(const bf16x8*)(Vs + row * 64 + c0 * 8);
      bf16x8 vf1 = *(const bf16x8*)(Vs + row * 64 + c1 * 8);
      accO[0][dt] = __builtin_amdgcn_mfma_f32_16x16x32_bf16(pfr[0][0], vf0, accO[0][dt], 0, 0, 0);
      accO[0][dt] = __builtin_amdgcn_mfma_f32_16x16x32_bf16(pfr[0][1], vf1, accO[0][dt], 0, 0, 0);
      accO[1][dt] = __builtin_amdgcn_mfma_f32_16x16x32_bf16(pfr[1][0], vf0, accO[1][dt], 0, 0, 0);
      accO[1][dt] = __builtin_amdgcn_mfma_f32_16x16x32_bf16(pfr[1][1], vf1, accO[1][dt], 0, 0, 0);
    }

    __syncthreads();   // all waves done reading Vs / Ks[cur] before overwrite
  }
#undef STAGE_K
#undef STAGE_V

  // epilogue: reduce l across 16 lanes, write O over this block's Q rows
#pragma unroll
  for (int g = 0; g < 2; ++g)
#pragma unroll
  for (int r = 0; r < 4; ++r) {
    float ps = lpart[g][r];
    ps += __shfl_xor(ps, 1, 64);
    ps += __shfl_xor(ps, 2, 64);
    ps += __shfl_xor(ps, 4, 64);
    ps += __shfl_xor(ps, 8, 64);
    const int qi = q0 + g * 16 + quad * 4 + r;
    const float invl = 1.0f / ps;
#pragma unroll
    for (int dt = 0; dt < 8; ++dt)
      Qh[(size_t)qi * HDIM + dt * 16 + ln] = __float2bfloat16(accO[g][dt][r] * invl);
  }
}

extern "C" void kernel_launch(void* const* d_in, const int* in_sizes, int n_in,
                              void* d_out, int out_size, void* d_ws, size_t ws_size,
                              hipStream_t stream) {
  const float* hidden   = (const float*)d_in[0];
  const float* residual = (const float*)d_in[1];
  const float* alibi    = (const float*)d_in[2];
  const int*   mask     = (const int*)d_in[3];
  const float* qkv_w    = (const float*)d_in[4];
  const float* qkv_b    = (const float*)d_in[5];
  const float* dense_w  = (const float*)d_in[6];
  const float* dense_b  = (const float*)d_in[7];
  float* out = (float*)d_out;   // reference output dtype is float32

  const size_t per  = (size_t)NH_TOT * S_LEN * HDIM;  // 16,777,216 elems
  const size_t nWq  = (size_t)3 * HSZ * HSZ;          // 50,331,648 elems
  __hip_bfloat16* Qb = (__hip_bfloat16*)d_ws;
  __hip_bfloat16* Kb = Qb + per;
  __hip_bfloat16* Vt = Kb + per;
  __hip_bfloat16* Ah = Vt + per;        // hidden bf16, later reused for dense_w
  __hip_bfloat16* Wq = Ah + per;        // qkv_w bf16; later reused for mask bits
  unsigned long long* mp = (unsigned long long*)Wq;   // 1 MB, after qkv_gemm

  // convert f32 inputs to bf16
  cvt_f32_bf16<<<(int)(per / 4 / 256), 256, 0, stream>>>(hidden, Ah, per);
  cvt_f32_bf16<<<(int)(nWq / 4 / 256), 256, 0, stream>>>(qkv_w, Wq, nWq);

  qkv_gemm<<<dim3(768), 512, 0, stream>>>(Ah, Wq, qkv_b, Qb, Kb, Vt);

  // Wq dead now -> pack mask bits there; Ah dead -> reuse for dense_w bf16
  pack_mask<<<(int)(2u * S_LEN * S_LEN / 256), 256, 0, stream>>>(mask, mp);
  cvt_f32_bf16<<<(int)(per / 4 / 256), 256, 0, stream>>>(dense_w, Ah, per);

  flash_attn<<<dim3(1024), 256, 0, stream>>>(Qb, Kb, Vt, alibi, mp);
  dense_gemm<<<dim3(256), 512, 0, stream>>>(Qb, Ah, dense_b, residual, out);
}